// Round 1
// baseline (908.800 us; speedup 1.0000x reference)
//
#include <hip/hip_runtime.h>
#include <cmath>

// Problem constants (B=1): x (1,4,64,128,128) f32
#define Tt 4
#define Cc 64
#define Hh 128
#define Ww 128
#define HW_ 16384      // H*W
#define THW_ 65536     // T*H*W
#define CHW_ 1048576   // C*H*W (= stride per t in x layout (T,C,H,W))
#define NT 27
#define OCC 81

// ws layout (in floats):
//   off : [0, 5308416)            81 * 65536
//   owt : [5308416, +139968)      offset_w transposed -> [c][k][oc]
//   wt  : [5448384, +110592)      weight transposed   -> [k][c][o]
//   xt  : [5558976, +4194304)     x transposed        -> [t][h][w][c]

__global__ __launch_bounds__(256) void prep_weights(
    const float* __restrict__ offset_w,
    const float* __restrict__ weight,
    float* __restrict__ owt,
    float* __restrict__ wt)
{
  int i = blockIdx.x * 256 + threadIdx.x;
  if (i < OCC * Cc * NT) {
    int k = i % NT;
    int c = (i / NT) % Cc;
    int oc = i / (NT * Cc);
    owt[(c * NT + k) * OCC + oc] = offset_w[i];
  }
  if (i < Cc * Cc * NT) {
    int k = i % NT;
    int c = (i / NT) % Cc;
    int o = i / (NT * Cc);
    wt[(k * Cc + c) * Cc + o] = weight[i];
  }
}

__global__ __launch_bounds__(256) void transpose_x(
    const float* __restrict__ x, float* __restrict__ xt)
{
  __shared__ float tile[64][65];
  int b = blockIdx.x;            // (t*128 + h)*2 + wblk
  int wblk = b & 1;
  int th = b >> 1;
  int h = th & 127;
  int t = th >> 7;
  int w0 = wblk * 64;
  int lane = threadIdx.x & 63;
  int quad = threadIdx.x >> 6;   // 0..3
  #pragma unroll
  for (int cc = 0; cc < 16; ++cc) {
    int c = cc * 4 + quad;
    tile[c][lane] = x[t * CHW_ + c * HW_ + h * Ww + w0 + lane];
  }
  __syncthreads();
  #pragma unroll
  for (int ww = 0; ww < 16; ++ww) {
    int w = ww * 4 + quad;
    xt[(size_t)(t * HW_ + h * Ww + w0 + w) * 64 + lane] = tile[lane][w];
  }
}

// Offset conv: off[oc][t][h][w] = sum_{c,kt,kh,kw} x[t+kt-1][c][h+kh-1][w+kw-1] * W
// grid (256, 3): blockIdx.x covers 256 positions, blockIdx.y picks 27 oc.
__global__ __launch_bounds__(256) void offconv(
    const float* __restrict__ x,
    const float* __restrict__ owt,
    const float* __restrict__ ob,
    float* __restrict__ off)
{
  int p = blockIdx.x * 256 + threadIdx.x;   // 0..65535
  int ocb = 27 * blockIdx.y;                // 0, 27, 54
  int t = p >> 14;
  int h = (p >> 7) & 127;
  int w = p & 127;
  float acc[27];
  #pragma unroll
  for (int j = 0; j < 27; ++j) acc[j] = 0.f;
  for (int kt = 0; kt < 3; ++kt) {
    int ts = t + kt - 1;
    bool tok = (unsigned)ts < 4u;
    int tsc = min(max(ts, 0), 3);
    for (int kh = 0; kh < 3; ++kh) {
      int hs = h + kh - 1;
      bool hok = (unsigned)hs < 128u;
      int hsc = min(max(hs, 0), 127);
      for (int kw = 0; kw < 3; ++kw) {
        int wsd = w + kw - 1;
        bool wok = (unsigned)wsd < 128u;
        int wsc = min(max(wsd, 0), 127);
        bool okv = tok && hok && wok;
        const float* xp = x + tsc * CHW_ + hsc * Ww + wsc;
        int kidx = (kt * 3 + kh) * 3 + kw;
        const float* wbase = owt + kidx * OCC + ocb;   // + c*27*81 per channel
        for (int c = 0; c < Cc; ++c) {
          float xv = xp[c * HW_];
          xv = okv ? xv : 0.f;
          const float* wr = wbase + c * (NT * OCC);    // wave-uniform -> s_load
          #pragma unroll
          for (int j = 0; j < 27; ++j) acc[j] = fmaf(xv, wr[j], acc[j]);
        }
      }
    }
  }
  #pragma unroll
  for (int j = 0; j < 27; ++j)
    off[(size_t)(ocb + j) * THW_ + p] = acc[j] + ob[ocb + j];
}

// Deformable sample + per-tap 64x64 matmul + residual epilogue.
// Block = 256 threads = 4 waves; block covers 64 consecutive positions (same t,h).
// Phase A: wave i samples channels [16i,16i+16) for all 64 positions -> LDS s[c][p].
// Phase B: wave i accumulates output channels [16i,16i+16) for p = lane.
__global__ __launch_bounds__(256) void deform(
    const float* __restrict__ x,
    const float* __restrict__ xt,
    const float* __restrict__ off,
    const float* __restrict__ wt,
    const float* __restrict__ gamma,
    float* __restrict__ out)
{
  __shared__ float smem[64 * 64];
  int lane = threadIdx.x & 63;
  int wavei = __builtin_amdgcn_readfirstlane(threadIdx.x >> 6);
  int cg = wavei * 16;
  int p0 = blockIdx.x * 64;
  int t = p0 >> 14;
  int h = (p0 >> 7) & 127;
  int w0 = p0 & 127;
  int w = w0 + lane;
  int pidx = p0 + lane;
  float acc[16];
  #pragma unroll
  for (int j = 0; j < 16; ++j) acc[j] = 0.f;

  for (int k = 0; k < NT; ++k) {
    int kt = k / 9;
    int kh = (k / 3) % 3;
    int kw = k % 3;
    float dt = off[(size_t)(0 * NT + k) * THW_ + pidx];
    float dh = off[(size_t)(1 * NT + k) * THW_ + pidx];
    float dw = off[(size_t)(2 * NT + k) * THW_ + pidx];
    float tf = (float)(t + kt - 1) + dt;
    float hf = (float)(h + kh - 1) + dh;
    float wf = (float)(w + kw - 1) + dw;
    float tF = floorf(tf), hF = floorf(hf), wF = floorf(wf);
    float lt = tf - tF, lh = hf - hF, lw = wf - wF;
    int t0 = (int)tF, h0 = (int)hF, wq = (int)wF;
    float wtv[2], whv[2], wwv[2];
    int tiv[2], hiv[2], wiv[2];
    #pragma unroll
    for (int a = 0; a < 2; ++a) {
      int ti = t0 + a;
      wtv[a] = (a ? lt : 1.f - lt) * (((unsigned)ti < 4u) ? 1.f : 0.f);
      tiv[a] = min(max(ti, 0), 3);
      int hi = h0 + a;
      whv[a] = (a ? lh : 1.f - lh) * (((unsigned)hi < 128u) ? 1.f : 0.f);
      hiv[a] = min(max(hi, 0), 127);
      int wi = wq + a;
      wwv[a] = (a ? lw : 1.f - lw) * (((unsigned)wi < 128u) ? 1.f : 0.f);
      wiv[a] = min(max(wi, 0), 127);
    }
    float v[16];
    #pragma unroll
    for (int j = 0; j < 16; ++j) v[j] = 0.f;
    #pragma unroll
    for (int a = 0; a < 2; ++a)
      #pragma unroll
      for (int bb = 0; bb < 2; ++bb)
        #pragma unroll
        for (int cI = 0; cI < 2; ++cI) {
          float wc = wtv[a] * whv[bb] * wwv[cI];
          const float4* xp = reinterpret_cast<const float4*>(
              xt + (size_t)(tiv[a] * HW_ + hiv[bb] * Ww + wiv[cI]) * 64 + cg);
          #pragma unroll
          for (int q = 0; q < 4; ++q) {
            float4 xv = xp[q];
            v[4 * q + 0] = fmaf(wc, xv.x, v[4 * q + 0]);
            v[4 * q + 1] = fmaf(wc, xv.y, v[4 * q + 1]);
            v[4 * q + 2] = fmaf(wc, xv.z, v[4 * q + 2]);
            v[4 * q + 3] = fmaf(wc, xv.w, v[4 * q + 3]);
          }
        }
    #pragma unroll
    for (int j = 0; j < 16; ++j) smem[(cg + j) * 64 + lane] = v[j];
    __syncthreads();
    // Phase B: 16-oc register tile, scalar (wave-uniform, contiguous) weights
    const float* wk = wt + k * Cc * Cc + cg;
    for (int c2 = 0; c2 < Cc; ++c2) {
      float sv = smem[c2 * 64 + lane];
      const float* wr = wk + c2 * Cc;   // 16 consecutive floats, uniform
      #pragma unroll
      for (int j = 0; j < 16; ++j) acc[j] = fmaf(sv, wr[j], acc[j]);
    }
    __syncthreads();
  }
  float g = gamma[0];
  #pragma unroll
  for (int j = 0; j < 16; ++j) {
    int o = cg + j;
    size_t oi = (size_t)t * CHW_ + (size_t)o * HW_ + (size_t)h * Ww + w;
    out[oi] = fmaf(g, acc[j], x[oi]);
  }
}

extern "C" void kernel_launch(void* const* d_in, const int* in_sizes, int n_in,
                              void* d_out, int out_size, void* d_ws, size_t ws_size,
                              hipStream_t stream) {
  (void)in_sizes; (void)n_in; (void)out_size; (void)ws_size;
  const float* x        = (const float*)d_in[0];
  const float* offset_w = (const float*)d_in[1];
  const float* offset_b = (const float*)d_in[2];
  const float* weight   = (const float*)d_in[3];
  const float* gamma    = (const float*)d_in[4];
  float* out = (float*)d_out;
  float* wsf = (float*)d_ws;
  float* off = wsf;                               // 5308416
  float* owt = wsf + 5308416;                     // 139968
  float* wtb = wsf + 5308416 + 139968;            // 110592
  float* xt  = wsf + 5308416 + 139968 + 110592;   // 4194304

  hipLaunchKernelGGL(prep_weights, dim3(547), dim3(256), 0, stream,
                     offset_w, weight, owt, wtb);
  hipLaunchKernelGGL(transpose_x, dim3(1024), dim3(256), 0, stream, x, xt);
  hipLaunchKernelGGL(offconv, dim3(256, 3), dim3(256), 0, stream,
                     x, owt, offset_b, off);
  hipLaunchKernelGGL(deform, dim3(1024), dim3(256), 0, stream,
                     x, xt, off, wtb, gamma, out);
}

// Round 2
// 372.072 us; speedup vs baseline: 2.4425x; 2.4425x over previous
//
#include <hip/hip_runtime.h>
#include <cmath>

// Problem constants (B=1): x (1,4,64,128,128) f32
#define Cc 64
#define Hh 128
#define Ww 128
#define HW_ 16384      // H*W
#define THW_ 65536     // T*H*W
#define CHW_ 1048576   // C*H*W
#define NT 27

typedef unsigned short ushort_t;
typedef __bf16 bf16x8 __attribute__((ext_vector_type(8)));
typedef float floatx4 __attribute__((ext_vector_type(4)));

static __device__ inline ushort_t f2b(float f) {
  unsigned u = __float_as_uint(f);
  unsigned r = u + 0x7FFFu + ((u >> 16) & 1u);   // RNE
  return (ushort_t)(r >> 16);
}
static __device__ inline float b2f(ushort_t u) {
  return __uint_as_float(((unsigned)u) << 16);
}

// ws layout (floats):
//   off    : [0, 5308416)           81 * 65536 f32
//   xt     : [5308416, +2097152)    x -> [t][h][w][c] bf16 (4194304 ushorts)
//   wfrag  : [7405568, +55296)      deform weight B-frags, 110592 bf16
//   w2frag : [7460864, +82944)      offconv weight B-frags, 165888 bf16

// Pack weights into MFMA fragment order.
// Fragment addressing (mfma_f32_16x16x32_bf16, B-operand): lane&15 = n (16-dim),
// k-within-32 = (lane>>4)*8 + j, two k-halves per 64-deep K slice.
__global__ __launch_bounds__(256) void prep(
    const float* __restrict__ offset_w,
    const float* __restrict__ weight,
    ushort_t* __restrict__ w2frag,
    ushort_t* __restrict__ wfrag)
{
  int e = blockIdx.x * 256 + threadIdx.x;
  if (e < 165888) {   // offconv: 27 taps x 6 oc-tiles x 2 khalf x 64 lanes x 8
    int j = e & 7, ln = (e >> 3) & 63, kh2 = (e >> 9) & 1, r = e >> 10;
    int ot = r % 6, k = r / 6;
    int oc = ot * 16 + (ln & 15);
    int c  = kh2 * 32 + (ln >> 4) * 8 + j;
    float v = (oc < 81) ? offset_w[(oc * 64 + c) * 27 + k] : 0.f;
    w2frag[e] = f2b(v);
  }
  if (e < 110592) {   // deform: 27 taps x 4 oc-tiles x 2 khalf x 64 lanes x 8
    int j = e & 7, ln = (e >> 3) & 63, kh2 = (e >> 9) & 1, r = e >> 10;
    int ot = r & 3, k = r >> 2;
    int o = ot * 16 + (ln & 15);
    int c = kh2 * 32 + (ln >> 4) * 8 + j;
    wfrag[e] = f2b(weight[(o * 64 + c) * 27 + k]);
  }
}

__global__ __launch_bounds__(256) void transpose_x(
    const float* __restrict__ x, ushort_t* __restrict__ xt)
{
  __shared__ float tile[64][65];
  int b = blockIdx.x;            // (t*128 + h)*2 + wblk
  int wblk = b & 1;
  int th = b >> 1;
  int h = th & 127;
  int t = th >> 7;
  int w0 = wblk * 64;
  int lane = threadIdx.x & 63;
  int quad = threadIdx.x >> 6;
  #pragma unroll
  for (int cc = 0; cc < 16; ++cc) {
    int c = cc * 4 + quad;
    tile[c][lane] = x[t * CHW_ + c * HW_ + h * Ww + w0 + lane];
  }
  __syncthreads();
  #pragma unroll
  for (int ww = 0; ww < 16; ++ww) {
    int w = ww * 4 + quad;
    xt[(size_t)(t * HW_ + h * Ww + w0 + w) * 64 + lane] = f2b(tile[lane][w]);
  }
}

// Offset conv as MFMA GEMM: off[96 oc (81 used)][64 p] per block,
// K = 27 taps x 64 c. Each wave owns p-tile = wavei (16 positions): builds
// S[p][c] bf16 rows for its tile, A-frag = S, B-frag = packed offset_w.
// No barriers in the tap loop (each wave reads only rows it wrote).
__global__ __launch_bounds__(256) void offconv(
    const ushort_t* __restrict__ xt,
    const ushort_t* __restrict__ w2frag,
    const float* __restrict__ ob,
    float* __restrict__ off)
{
  __shared__ ushort_t S[64 * 72];     // [p][c], stride 72 (16B-aligned rows)
  __shared__ float Dbuf[96 * 65];
  int lane = threadIdx.x & 63;
  int wavei = __builtin_amdgcn_readfirstlane(threadIdx.x >> 6);
  int quad = lane >> 4;
  int m16 = lane & 15;
  int p0 = blockIdx.x * 64;
  int t = p0 >> 14;
  int h = (p0 >> 7) & 127;
  int w0 = p0 & 127;

  floatx4 acc[6];
  #pragma unroll
  for (int i = 0; i < 6; ++i) acc[i] = (floatx4){0.f, 0.f, 0.f, 0.f};

  for (int k = 0; k < NT; ++k) {
    int kt = k / 9, kh = (k / 3) % 3, kw = k % 3;
    int ts = t + kt - 1;
    int hs = h + kh - 1;
    bool rowok = ((unsigned)ts < 4u) && ((unsigned)hs < 128u);
    if (!rowok) continue;    // S-contribution is all-zero: skip tap entirely
    int sbase = ts * HW_ + hs * Ww;
    // build S rows for this wave's 16 positions (lane = channel)
    #pragma unroll
    for (int i = 0; i < 16; ++i) {
      int pl = wavei * 16 + i;
      int wc = w0 + pl + kw - 1;
      bool vok = (unsigned)wc < 128u;
      int sc = sbase + min(max(wc, 0), 127);
      ushort_t u = xt[(size_t)sc * 64 + lane];
      S[pl * 72 + lane] = vok ? u : (ushort_t)0;
    }
    // A-frags from own rows
    const ushort_t* srow = &S[(wavei * 16 + m16) * 72 + quad * 8];
    bf16x8 af0 = *(const bf16x8*)(srow);
    bf16x8 af1 = *(const bf16x8*)(srow + 32);
    #pragma unroll
    for (int ot = 0; ot < 6; ++ot) {
      const ushort_t* wb = w2frag + (size_t)((k * 6 + ot) * 2) * 512 + lane * 8;
      bf16x8 b0 = *(const bf16x8*)(wb);
      bf16x8 b1 = *(const bf16x8*)(wb + 512);
      acc[ot] = __builtin_amdgcn_mfma_f32_16x16x32_bf16(af0, b0, acc[ot], 0, 0, 0);
      acc[ot] = __builtin_amdgcn_mfma_f32_16x16x32_bf16(af1, b1, acc[ot], 0, 0, 0);
    }
  }
  // stage D to LDS: D col = lane&15 = oc-in-tile, row = quad*4+reg = p-in-tile
  #pragma unroll
  for (int ot = 0; ot < 6; ++ot)
    #pragma unroll
    for (int r = 0; r < 4; ++r)
      Dbuf[(ot * 16 + m16) * 65 + wavei * 16 + quad * 4 + r] = acc[ot][r];
  __syncthreads();
  for (int i = threadIdx.x; i < 81 * 64; i += 256) {
    int oc = i >> 6, p = i & 63;
    off[(size_t)oc * THW_ + p0 + p] = Dbuf[oc * 65 + p] + ob[oc];
  }
}

// Deformable sample + MFMA GEMM: out[64 oc][64 p] per block, K = 27x64.
// Wave owns p-tile = wavei. Gather: lane = channel, site uniform via readlane.
__global__ __launch_bounds__(256) void deform(
    const float* __restrict__ x,
    const ushort_t* __restrict__ xt,
    const float* __restrict__ off,
    const ushort_t* __restrict__ wfrag,
    const float* __restrict__ gamma,
    float* __restrict__ out)
{
  __shared__ ushort_t S[64 * 72];
  __shared__ float Dbuf[64 * 65];
  int lane = threadIdx.x & 63;
  int wavei = __builtin_amdgcn_readfirstlane(threadIdx.x >> 6);
  int quad = lane >> 4;
  int m16 = lane & 15;
  int p0 = blockIdx.x * 64;
  int t = p0 >> 14;
  int h = (p0 >> 7) & 127;
  int w0 = p0 & 127;

  floatx4 acc[4];
  #pragma unroll
  for (int i = 0; i < 4; ++i) acc[i] = (floatx4){0.f, 0.f, 0.f, 0.f};

  #pragma unroll 1
  for (int k = 0; k < NT; ++k) {
    int kt = k / 9, kh = (k / 3) % 3, kw = k % 3;
    // --- meta: every lane computes corners for position (lane&15) of this wave's tile
    int pml = wavei * 16 + m16;           // position within block
    int pm = p0 + pml;                    // global position
    float dt = off[(size_t)(0 * NT + k) * THW_ + pm];
    float dh = off[(size_t)(1 * NT + k) * THW_ + pm];
    float dw = off[(size_t)(2 * NT + k) * THW_ + pm];
    float tf = (float)(t + kt - 1) + dt;
    float hf = (float)(h + kh - 1) + dh;
    float wf = (float)(w0 + pml + kw - 1) + dw;
    float tF = floorf(tf), hF = floorf(hf), wF = floorf(wf);
    float lt = tf - tF, lh = hf - hF, lw = wf - wF;
    int t0 = (int)tF, h0 = (int)hF, wq = (int)wF;
    float wtv[2], whv[2], wwv[2];
    int tiv[2], hiv[2], wiv[2];
    #pragma unroll
    for (int a = 0; a < 2; ++a) {
      int ti = t0 + a;
      wtv[a] = (a ? lt : 1.f - lt) * (((unsigned)ti < 4u) ? 1.f : 0.f);
      tiv[a] = min(max(ti, 0), 3);
      int hi = h0 + a;
      whv[a] = (a ? lh : 1.f - lh) * (((unsigned)hi < 128u) ? 1.f : 0.f);
      hiv[a] = min(max(hi, 0), 127);
      int wi = wq + a;
      wwv[a] = (a ? lw : 1.f - lw) * (((unsigned)wi < 128u) ? 1.f : 0.f);
      wiv[a] = min(max(wi, 0), 127);
    }
    int sites[8];
    float cws[8];
    #pragma unroll
    for (int a = 0; a < 2; ++a)
      #pragma unroll
      for (int b = 0; b < 2; ++b)
        #pragma unroll
        for (int c = 0; c < 2; ++c) {
          sites[a * 4 + b * 2 + c] = (tiv[a] * Hh + hiv[b]) * Ww + wiv[c];
          cws[a * 4 + b * 2 + c] = wtv[a] * whv[b] * wwv[c];
        }
    // --- gather: lane = channel; per position, 8 wave-uniform site rows
    #pragma unroll 4
    for (int i = 0; i < 16; ++i) {
      float v = 0.f;
      #pragma unroll
      for (int c8 = 0; c8 < 8; ++c8) {
        int s = __builtin_amdgcn_readlane(sites[c8], i);
        float wv = __uint_as_float(
            (unsigned)__builtin_amdgcn_readlane((int)__float_as_uint(cws[c8]), i));
        v = fmaf(wv, b2f(xt[(size_t)s * 64 + lane]), v);
      }
      S[(wavei * 16 + i) * 72 + lane] = f2b(v);
    }
    // --- MFMA: A = own S rows, B = packed deform weights
    const ushort_t* srow = &S[(wavei * 16 + m16) * 72 + quad * 8];
    bf16x8 af0 = *(const bf16x8*)(srow);
    bf16x8 af1 = *(const bf16x8*)(srow + 32);
    #pragma unroll
    for (int ot = 0; ot < 4; ++ot) {
      const ushort_t* wb = wfrag + (size_t)((k * 4 + ot) * 2) * 512 + lane * 8;
      bf16x8 b0 = *(const bf16x8*)(wb);
      bf16x8 b1 = *(const bf16x8*)(wb + 512);
      acc[ot] = __builtin_amdgcn_mfma_f32_16x16x32_bf16(af0, b0, acc[ot], 0, 0, 0);
      acc[ot] = __builtin_amdgcn_mfma_f32_16x16x32_bf16(af1, b1, acc[ot], 0, 0, 0);
    }
  }
  // stage D: col = lane&15 = oc-in-tile, row = quad*4+reg = p-in-tile
  #pragma unroll
  for (int ot = 0; ot < 4; ++ot)
    #pragma unroll
    for (int r = 0; r < 4; ++r)
      Dbuf[(ot * 16 + m16) * 65 + wavei * 16 + quad * 4 + r] = acc[ot][r];
  __syncthreads();
  float g = gamma[0];
  for (int i = threadIdx.x; i < 64 * 64; i += 256) {
    int oc = i >> 6, p = i & 63;
    size_t oi = (size_t)t * CHW_ + (size_t)oc * HW_ + (size_t)h * Ww + w0 + p;
    out[oi] = fmaf(g, Dbuf[oc * 65 + p], x[oi]);
  }
}

extern "C" void kernel_launch(void* const* d_in, const int* in_sizes, int n_in,
                              void* d_out, int out_size, void* d_ws, size_t ws_size,
                              hipStream_t stream) {
  (void)in_sizes; (void)n_in; (void)out_size; (void)ws_size;
  const float* x        = (const float*)d_in[0];
  const float* offset_w = (const float*)d_in[1];
  const float* offset_b = (const float*)d_in[2];
  const float* weight   = (const float*)d_in[3];
  const float* gamma    = (const float*)d_in[4];
  float* out = (float*)d_out;
  float* wsf = (float*)d_ws;
  float*    off    = wsf;                               // 5308416 f32
  ushort_t* xt     = (ushort_t*)(wsf + 5308416);        // 4194304 bf16
  ushort_t* wfrag  = (ushort_t*)(wsf + 7405568);        // 110592 bf16
  ushort_t* w2frag = (ushort_t*)(wsf + 7460864);        // 165888 bf16

  hipLaunchKernelGGL(prep, dim3(648), dim3(256), 0, stream,
                     offset_w, weight, w2frag, wfrag);
  hipLaunchKernelGGL(transpose_x, dim3(1024), dim3(256), 0, stream, x, xt);
  hipLaunchKernelGGL(offconv, dim3(1024), dim3(256), 0, stream,
                     xt, w2frag, offset_b, off);
  hipLaunchKernelGGL(deform, dim3(1024), dim3(256), 0, stream,
                     x, xt, off, wfrag, gamma, out);
}

// Round 4
// 245.361 us; speedup vs baseline: 3.7039x; 1.5164x over previous
//
#include <hip/hip_runtime.h>
#include <cmath>

// Problem constants (B=1): x (1,4,64,128,128) f32
#define Cc 64
#define Hh 128
#define Ww 128
#define HW_ 16384
#define THW_ 65536
#define CHW_ 1048576
#define NT 27

typedef unsigned short ushort_t;
typedef _Float16 f16x2 __attribute__((ext_vector_type(2)));
typedef _Float16 f16x8 __attribute__((ext_vector_type(8)));
typedef __fp16 fp16x2_alt __attribute__((ext_vector_type(2)));
typedef float floatx4 __attribute__((ext_vector_type(4)));

union U32H2 { unsigned u; f16x2 h; };

static __device__ inline ushort_t f2h(float f) {
  union { _Float16 h; ushort_t u; } v;
  v.h = (_Float16)f;
  return v.u;
}

static __device__ inline unsigned pk2(float a) {
  union { fp16x2_alt h; unsigned u; } v;
  v.h = __builtin_amdgcn_cvt_pkrtz(a, a);
  return v.u;
}

#if defined(__has_builtin)
#if __has_builtin(__builtin_amdgcn_make_buffer_rsrc) && __has_builtin(__builtin_amdgcn_raw_buffer_load_b32)
#define USE_BUF 1
#endif
#endif
#ifndef USE_BUF
#define USE_BUF 0
#endif

struct XtBuf {
#if USE_BUF
  __amdgpu_buffer_rsrc_t r;
#else
  const unsigned* p;
#endif
};

static __device__ inline XtBuf mkbuf(const ushort_t* xt) {
  XtBuf b;
#if USE_BUF
  b.r = __builtin_amdgcn_make_buffer_rsrc((void*)xt, (short)0, 8388608, 0x00020000);
#else
  b.p = (const unsigned*)xt;
#endif
  return b;
}

static __device__ inline unsigned xload(const XtBuf& b, unsigned voff) {
#if USE_BUF
  return (unsigned)__builtin_amdgcn_raw_buffer_load_b32(b.r, (int)voff, 0, 0);
#else
  return b.p[voff >> 2];
#endif
}

// ws layout (floats):
//   off    : [0, 5308416)           81 * 65536 f32
//   xt     : [5308416, +2097152)    x -> [t][h][w][c] f16 (4194304 ushorts)
//   wfrag  : [7405568, +55296)      deform weight B-frags, 110592 f16
//   w2frag : [7460864, +82944)      offconv weight B-frags, 165888 f16

__global__ __launch_bounds__(256) void prep(
    const float* __restrict__ offset_w,
    const float* __restrict__ weight,
    ushort_t* __restrict__ w2frag,
    ushort_t* __restrict__ wfrag)
{
  int e = blockIdx.x * 256 + threadIdx.x;
  if (e < 165888) {   // offconv: 27 taps x 6 oc-tiles x 2 khalf x 64 lanes x 8
    int j = e & 7, ln = (e >> 3) & 63, kh2 = (e >> 9) & 1, r = e >> 10;
    int ot = r % 6, k = r / 6;
    int oc = ot * 16 + (ln & 15);
    int c  = kh2 * 32 + (ln >> 4) * 8 + j;
    float v = (oc < 81) ? offset_w[(oc * 64 + c) * 27 + k] : 0.f;
    w2frag[e] = f2h(v);
  }
  if (e < 110592) {   // deform: 27 taps x 4 oc-tiles x 2 khalf x 64 lanes x 8
    int j = e & 7, ln = (e >> 3) & 63, kh2 = (e >> 9) & 1, r = e >> 10;
    int ot = r & 3, k = r >> 2;
    int o = ot * 16 + (ln & 15);
    int c = kh2 * 32 + (ln >> 4) * 8 + j;
    wfrag[e] = f2h(weight[(o * 64 + c) * 27 + k]);
  }
}

__global__ __launch_bounds__(256) void transpose_x(
    const float* __restrict__ x, ushort_t* __restrict__ xt)
{
  __shared__ float tile[64][65];
  int b = blockIdx.x;
  int wblk = b & 1;
  int th = b >> 1;
  int h = th & 127;
  int t = th >> 7;
  int w0 = wblk * 64;
  int lane = threadIdx.x & 63;
  int quad = threadIdx.x >> 6;
  #pragma unroll
  for (int cc = 0; cc < 16; ++cc) {
    int c = cc * 4 + quad;
    tile[c][lane] = x[t * CHW_ + c * HW_ + h * Ww + w0 + lane];
  }
  __syncthreads();
  #pragma unroll
  for (int ww = 0; ww < 16; ++ww) {
    int w = ww * 4 + quad;
    xt[(size_t)(t * HW_ + h * Ww + w0 + w) * 64 + lane] = f2h(tile[lane][w]);
  }
}

// Offset conv as MFMA GEMM: off[96 oc (81 used)][64 p] per block, K = 27x64.
__global__ __launch_bounds__(256) void offconv(
    const ushort_t* __restrict__ xt,
    const ushort_t* __restrict__ w2frag,
    const float* __restrict__ ob,
    float* __restrict__ off)
{
  __shared__ __align__(16) char lds[24960];   // S (9216) | Dbuf (24960) aliased
  ushort_t* S = (ushort_t*)lds;               // [64 pos][72 f16]
  float* Dbuf = (float*)lds;                  // [96 oc][65]
  int lane = threadIdx.x & 63;
  int wavei = __builtin_amdgcn_readfirstlane(threadIdx.x >> 6);
  int quad = lane >> 4;
  int m16 = lane & 15;
  int hlf = lane >> 5;
  int lo4 = (lane & 31) * 4;
  int p0 = blockIdx.x * 64;
  int t = p0 >> 14;
  int h = (p0 >> 7) & 127;
  int w0 = p0 & 127;
  XtBuf xb = mkbuf(xt);

  floatx4 acc[6];
  #pragma unroll
  for (int i = 0; i < 6; ++i) acc[i] = (floatx4){0.f, 0.f, 0.f, 0.f};

  for (int k = 0; k < NT; ++k) {
    int kt = k / 9, kh = (k / 3) % 3, kw = k % 3;
    int ts = t + kt - 1;
    int hs = h + kh - 1;
    bool rowok = ((unsigned)ts < 4u) && ((unsigned)hs < 128u);
    if (!rowok) continue;
    int sbase = ts * HW_ + hs * Ww;
    // S-build: 8 position-pairs; lane = (pos-half, channel-pair)
    #pragma unroll
    for (int j = 0; j < 8; ++j) {
      int prow = wavei * 16 + j * 2 + hlf;
      int wc = w0 + prow + kw - 1;
      bool ok = (unsigned)wc < 128u;
      int wcc = min(max(wc, 0), 127);
      unsigned voff = ((unsigned)(sbase + wcc) << 7) + lo4;
      unsigned d = xload(xb, voff);
      d = ok ? d : 0u;
      *(unsigned*)((char*)S + prow * 144 + lo4) = d;
    }
    const ushort_t* srow = S + (wavei * 16 + m16) * 72 + quad * 8;
    f16x8 af0 = *(const f16x8*)srow;
    f16x8 af1 = *(const f16x8*)(srow + 32);
    #pragma unroll
    for (int ot = 0; ot < 6; ++ot) {
      const ushort_t* wb = w2frag + (size_t)((k * 6 + ot) * 2) * 512 + lane * 8;
      f16x8 b0 = *(const f16x8*)(wb);
      f16x8 b1 = *(const f16x8*)(wb + 512);
      acc[ot] = __builtin_amdgcn_mfma_f32_16x16x32_f16(af0, b0, acc[ot], 0, 0, 0);
      acc[ot] = __builtin_amdgcn_mfma_f32_16x16x32_f16(af1, b1, acc[ot], 0, 0, 0);
    }
  }
  __syncthreads();   // S dead; Dbuf aliases it
  #pragma unroll
  for (int ot = 0; ot < 6; ++ot)
    #pragma unroll
    for (int r = 0; r < 4; ++r)
      Dbuf[(ot * 16 + m16) * 65 + wavei * 16 + quad * 4 + r] = acc[ot][r];
  __syncthreads();
  for (int i = threadIdx.x; i < 81 * 64; i += 256) {
    int oc = i >> 6, p = i & 63;
    off[(size_t)oc * THW_ + p0 + p] = Dbuf[oc * 65 + p] + ob[oc];
  }
}

// Deformable sample + MFMA GEMM: out[64 oc][64 p] per block, K = 27x64.
// Meta: lane (m16,quad) computes corners {2q,2q+1} of position m16 -> LDS.
// Gather: pair of positions per iteration, lane = (pos-half, ch-pair), pk f16 fma.
__global__ __launch_bounds__(256) void deform(
    const float* __restrict__ x,
    const ushort_t* __restrict__ xt,
    const float* __restrict__ off,
    const ushort_t* __restrict__ wfrag,
    const float* __restrict__ gamma,
    float* __restrict__ out)
{
  __shared__ __align__(16) char lds[16640];   // S(9216)+meta(4096) | Dbuf(16640)
  ushort_t* S = (ushort_t*)lds;               // [64 pos][72 f16]
  unsigned* meta = (unsigned*)(lds + 9216);   // [64 pos][8 corners][{site,w2}]
  float* Dbuf = (float*)lds;                  // [64 oc][65]
  int lane = threadIdx.x & 63;
  int wavei = __builtin_amdgcn_readfirstlane(threadIdx.x >> 6);
  int quad = lane >> 4;
  int m16 = lane & 15;
  int hlf = lane >> 5;
  int lo4 = (lane & 31) * 4;
  int p0 = blockIdx.x * 64;
  int t = p0 >> 14;
  int h = (p0 >> 7) & 127;
  int w0 = p0 & 127;
  XtBuf xb = mkbuf(xt);

  floatx4 acc[4];
  #pragma unroll
  for (int i = 0; i < 4; ++i) acc[i] = (floatx4){0.f, 0.f, 0.f, 0.f};

  int pl = wavei * 16 + m16;
  int pm = p0 + pl;
  int aq = quad >> 1, bq = quad & 1;

  #pragma unroll 1
  for (int k = 0; k < NT; ++k) {
    int kt = k / 9, kh = (k / 3) % 3, kw = k % 3;
    // --- meta: this lane handles position pl, (t,h)-corner (aq,bq), both w-corners
    float dt = off[(size_t)(0 * NT + k) * THW_ + pm];
    float dh = off[(size_t)(1 * NT + k) * THW_ + pm];
    float dw = off[(size_t)(2 * NT + k) * THW_ + pm];
    float tf = (float)(t + kt - 1) + dt;
    float hf = (float)(h + kh - 1) + dh;
    float wf = (float)(w0 + pl + kw - 1) + dw;
    float tF = floorf(tf), hF = floorf(hf), wF = floorf(wf);
    float lt = tf - tF, lh_ = hf - hF, lw_ = wf - wF;
    int t0 = (int)tF, h0 = (int)hF, wq_ = (int)wF;
    int ti = t0 + aq;
    float wt_ = (aq ? lt : 1.f - lt) * (((unsigned)ti < 4u) ? 1.f : 0.f);
    int tic = min(max(ti, 0), 3);
    int hi = h0 + bq;
    float wh_ = (bq ? lh_ : 1.f - lh_) * (((unsigned)hi < 128u) ? 1.f : 0.f);
    int hic = min(max(hi, 0), 127);
    int base2 = tic * HW_ + hic * Ww;
    float bw = wt_ * wh_;
    int wi0 = wq_;
    float ww0 = (1.f - lw_) * (((unsigned)wi0 < 128u) ? 1.f : 0.f);
    int wi0c = min(max(wi0, 0), 127);
    int wi1 = wq_ + 1;
    float ww1 = lw_ * (((unsigned)wi1 < 128u) ? 1.f : 0.f);
    int wi1c = min(max(wi1, 0), 127);
    uint4 me;
    me.x = (unsigned)(base2 + wi0c) << 7;
    me.y = pk2(bw * ww0);
    me.z = (unsigned)(base2 + wi1c) << 7;
    me.w = pk2(bw * ww1);
    *(uint4*)&meta[(pl * 8 + quad * 2) * 2] = me;

    // --- gather: 8 position-pairs
    #pragma unroll
    for (int j = 0; j < 8; ++j) {
      int prow = wavei * 16 + j * 2 + hlf;
      const uint4* mp = (const uint4*)&meta[prow * 16];
      uint4 c01 = mp[0], c23 = mp[1], c45 = mp[2], c67 = mp[3];
      U32H2 z; z.u = 0;
      f16x2 a2l = z.h, a2h = z.h;
      {
        unsigned d0 = xload(xb, c01.x + lo4);
        unsigned d1 = xload(xb, c01.z + lo4);
        unsigned d2 = xload(xb, c23.x + lo4);
        unsigned d3 = xload(xb, c23.z + lo4);
        unsigned d4 = xload(xb, c45.x + lo4);
        unsigned d5 = xload(xb, c45.z + lo4);
        unsigned d6 = xload(xb, c67.x + lo4);
        unsigned d7 = xload(xb, c67.z + lo4);
        U32H2 du, wu;
        du.u = d0; wu.u = c01.y; a2l += wu.h * du.h;
        du.u = d1; wu.u = c01.w; a2h += wu.h * du.h;
        du.u = d2; wu.u = c23.y; a2l += wu.h * du.h;
        du.u = d3; wu.u = c23.w; a2h += wu.h * du.h;
        du.u = d4; wu.u = c45.y; a2l += wu.h * du.h;
        du.u = d5; wu.u = c45.w; a2h += wu.h * du.h;
        du.u = d6; wu.u = c67.y; a2l += wu.h * du.h;
        du.u = d7; wu.u = c67.w; a2h += wu.h * du.h;
      }
      U32H2 res;
      res.h = a2l + a2h;
      *(unsigned*)((char*)S + prow * 144 + lo4) = res.u;
    }
    // --- MFMA
    const ushort_t* srow = S + (wavei * 16 + m16) * 72 + quad * 8;
    f16x8 af0 = *(const f16x8*)srow;
    f16x8 af1 = *(const f16x8*)(srow + 32);
    #pragma unroll
    for (int ot = 0; ot < 4; ++ot) {
      const ushort_t* wb = wfrag + (size_t)((k * 4 + ot) * 2) * 512 + lane * 8;
      f16x8 b0 = *(const f16x8*)(wb);
      f16x8 b1 = *(const f16x8*)(wb + 512);
      acc[ot] = __builtin_amdgcn_mfma_f32_16x16x32_f16(af0, b0, acc[ot], 0, 0, 0);
      acc[ot] = __builtin_amdgcn_mfma_f32_16x16x32_f16(af1, b1, acc[ot], 0, 0, 0);
    }
  }
  __syncthreads();   // S/meta dead; Dbuf aliases them
  #pragma unroll
  for (int ot = 0; ot < 4; ++ot)
    #pragma unroll
    for (int r = 0; r < 4; ++r)
      Dbuf[(ot * 16 + m16) * 65 + wavei * 16 + quad * 4 + r] = acc[ot][r];
  __syncthreads();
  float g = gamma[0];
  for (int i = threadIdx.x; i < 64 * 64; i += 256) {
    int oc = i >> 6, p = i & 63;
    size_t oi = (size_t)t * CHW_ + (size_t)oc * HW_ + (size_t)h * Ww + w0 + p;
    out[oi] = fmaf(g, Dbuf[oc * 65 + p], x[oi]);
  }
}

extern "C" void kernel_launch(void* const* d_in, const int* in_sizes, int n_in,
                              void* d_out, int out_size, void* d_ws, size_t ws_size,
                              hipStream_t stream) {
  (void)in_sizes; (void)n_in; (void)out_size; (void)ws_size;
  const float* x        = (const float*)d_in[0];
  const float* offset_w = (const float*)d_in[1];
  const float* offset_b = (const float*)d_in[2];
  const float* weight   = (const float*)d_in[3];
  const float* gamma    = (const float*)d_in[4];
  float* out = (float*)d_out;
  float* wsf = (float*)d_ws;
  float*    off    = wsf;                               // 5308416 f32
  ushort_t* xt     = (ushort_t*)(wsf + 5308416);        // 4194304 f16
  ushort_t* wfrag  = (ushort_t*)(wsf + 7405568);        // 110592 f16
  ushort_t* w2frag = (ushort_t*)(wsf + 7460864);        // 165888 f16

  hipLaunchKernelGGL(prep, dim3(648), dim3(256), 0, stream,
                     offset_w, weight, w2frag, wfrag);
  hipLaunchKernelGGL(transpose_x, dim3(1024), dim3(256), 0, stream, x, xt);
  hipLaunchKernelGGL(offconv, dim3(1024), dim3(256), 0, stream,
                     xt, w2frag, offset_b, off);
  hipLaunchKernelGGL(deform, dim3(1024), dim3(256), 0, stream,
                     x, xt, off, wfrag, gamma, out);
}

// Round 5
// 227.690 us; speedup vs baseline: 3.9914x; 1.0776x over previous
//
#include <hip/hip_runtime.h>
#include <cmath>

// Problem constants (B=1): x (1,4,64,128,128) f32
#define Cc 64
#define Hh 128
#define Ww 128
#define HW_ 16384
#define THW_ 65536
#define CHW_ 1048576
#define NT 27

typedef unsigned short ushort_t;
typedef _Float16 f16x2 __attribute__((ext_vector_type(2)));
typedef _Float16 f16x8 __attribute__((ext_vector_type(8)));
typedef __fp16 fp16x2_alt __attribute__((ext_vector_type(2)));
typedef float floatx4 __attribute__((ext_vector_type(4)));

union U32H2 { unsigned u; f16x2 h; };

static __device__ inline ushort_t f2h(float f) {
  union { _Float16 h; ushort_t u; } v;
  v.h = (_Float16)f;
  return v.u;
}

static __device__ inline unsigned pk2(float a) {
  union { fp16x2_alt h; unsigned u; } v;
  v.h = __builtin_amdgcn_cvt_pkrtz(a, a);
  return v.u;
}

#if defined(__has_builtin)
#if __has_builtin(__builtin_amdgcn_make_buffer_rsrc) && __has_builtin(__builtin_amdgcn_raw_buffer_load_b32)
#define USE_BUF 1
#endif
#endif
#ifndef USE_BUF
#define USE_BUF 0
#endif

struct XtBuf {
#if USE_BUF
  __amdgpu_buffer_rsrc_t r;
#else
  const unsigned* p;
#endif
};

static __device__ inline XtBuf mkbuf(const ushort_t* xt) {
  XtBuf b;
#if USE_BUF
  b.r = __builtin_amdgcn_make_buffer_rsrc((void*)xt, (short)0, 8388608, 0x00020000);
#else
  b.p = (const unsigned*)xt;
#endif
  return b;
}

static __device__ inline unsigned xload(const XtBuf& b, unsigned voff) {
#if USE_BUF
  return (unsigned)__builtin_amdgcn_raw_buffer_load_b32(b.r, (int)voff, 0, 0);
#else
  return b.p[voff >> 2];
#endif
}

// ws layout (floats):
//   off    : [0, 5308416)           81 * 65536 f32
//   xt     : [5308416, +2097152)    x -> [t][h][w][c] f16 (4194304 ushorts)
//   wfrag  : [7405568, +55296)      deform weight B-frags, 110592 f16
//   w2frag : [7460864, +82944)      offconv weight B-frags, 165888 f16

__global__ __launch_bounds__(256) void prep(
    const float* __restrict__ offset_w,
    const float* __restrict__ weight,
    ushort_t* __restrict__ w2frag,
    ushort_t* __restrict__ wfrag)
{
  int e = blockIdx.x * 256 + threadIdx.x;
  if (e < 165888) {   // offconv: 27 taps x 6 oc-tiles x 2 khalf x 64 lanes x 8
    int j = e & 7, ln = (e >> 3) & 63, kh2 = (e >> 9) & 1, r = e >> 10;
    int ot = r % 6, k = r / 6;
    int oc = ot * 16 + (ln & 15);
    int c  = kh2 * 32 + (ln >> 4) * 8 + j;
    float v = (oc < 81) ? offset_w[(oc * 64 + c) * 27 + k] : 0.f;
    w2frag[e] = f2h(v);
  }
  if (e < 110592) {   // deform: 27 taps x 4 oc-tiles x 2 khalf x 64 lanes x 8
    int j = e & 7, ln = (e >> 3) & 63, kh2 = (e >> 9) & 1, r = e >> 10;
    int ot = r & 3, k = r >> 2;
    int o = ot * 16 + (ln & 15);
    int c = kh2 * 32 + (ln >> 4) * 8 + j;
    wfrag[e] = f2h(weight[(o * 64 + c) * 27 + k]);
  }
}

__global__ __launch_bounds__(256) void transpose_x(
    const float* __restrict__ x, ushort_t* __restrict__ xt)
{
  __shared__ float tile[64][65];
  int b = blockIdx.x;
  int wblk = b & 1;
  int th = b >> 1;
  int h = th & 127;
  int t = th >> 7;
  int w0 = wblk * 64;
  int lane = threadIdx.x & 63;
  int quad = threadIdx.x >> 6;
  #pragma unroll
  for (int cc = 0; cc < 16; ++cc) {
    int c = cc * 4 + quad;
    tile[c][lane] = x[t * CHW_ + c * HW_ + h * Ww + w0 + lane];
  }
  __syncthreads();
  #pragma unroll
  for (int ww = 0; ww < 16; ++ww) {
    int w = ww * 4 + quad;
    xt[(size_t)(t * HW_ + h * Ww + w0 + w) * 64 + lane] = f2h(tile[lane][w]);
  }
}

// Offset conv as MFMA GEMM: off[96 oc (81 used)][64 p] per block, K = 27x64.
// Cross-tap pipelining: loads for tap k+1 issued before tap k's MFMAs.
__global__ __launch_bounds__(256, 4) void offconv(
    const ushort_t* __restrict__ xt,
    const ushort_t* __restrict__ w2frag,
    const float* __restrict__ ob,
    float* __restrict__ off)
{
  __shared__ __align__(16) char lds[24960];   // S (9216) | Dbuf (24960) aliased
  ushort_t* S = (ushort_t*)lds;               // [64 pos][72 f16]
  float* Dbuf = (float*)lds;                  // [96 oc][65]
  int lane = threadIdx.x & 63;
  int wavei = __builtin_amdgcn_readfirstlane(threadIdx.x >> 6);
  int quad = lane >> 4;
  int m16 = lane & 15;
  int hlf = lane >> 5;
  int lo4 = (lane & 31) * 4;
  int p0 = blockIdx.x * 64;
  int t = p0 >> 14;
  int h = (p0 >> 7) & 127;
  int w0 = p0 & 127;
  XtBuf xb = mkbuf(xt);

  floatx4 acc[6];
  #pragma unroll
  for (int i = 0; i < 6; ++i) acc[i] = (floatx4){0.f, 0.f, 0.f, 0.f};

  unsigned pd[8];

  auto issue = [&](int k) {
    int kt = k / 9, kh = (k / 3) % 3, kw = k % 3;
    int ts = t + kt - 1, hs = h + kh - 1;
    int tsc = min(max(ts, 0), 3);
    int hsc = min(max(hs, 0), 127);
    int sbase = tsc * HW_ + hsc * Ww;
    #pragma unroll
    for (int j = 0; j < 8; ++j) {
      int prow = wavei * 16 + j * 2 + hlf;
      int wc = w0 + prow + kw - 1;
      int wcc = min(max(wc, 0), 127);
      pd[j] = xload(xb, ((unsigned)(sbase + wcc) << 7) + lo4);
    }
  };

  issue(0);
  #pragma unroll 1
  for (int k = 0; k < NT; ++k) {
    int kt = k / 9, kh = (k / 3) % 3, kw = k % 3;
    int ts = t + kt - 1, hs = h + kh - 1;
    bool rowok = ((unsigned)ts < 4u) && ((unsigned)hs < 128u);
    // write current tap's staged loads to S (masked)
    #pragma unroll
    for (int j = 0; j < 8; ++j) {
      int prow = wavei * 16 + j * 2 + hlf;
      int wc = w0 + prow + kw - 1;
      bool ok = rowok && ((unsigned)wc < 128u);
      *(unsigned*)((char*)S + prow * 144 + lo4) = ok ? pd[j] : 0u;
    }
    // issue next tap's loads (in flight during MFMAs)
    issue(k + 1 < NT ? k + 1 : NT - 1);
    const ushort_t* srow = S + (wavei * 16 + m16) * 72 + quad * 8;
    f16x8 af0 = *(const f16x8*)srow;
    f16x8 af1 = *(const f16x8*)(srow + 32);
    #pragma unroll
    for (int ot = 0; ot < 6; ++ot) {
      const ushort_t* wb = w2frag + (size_t)((k * 6 + ot) * 2) * 512 + lane * 8;
      f16x8 b0 = *(const f16x8*)(wb);
      f16x8 b1 = *(const f16x8*)(wb + 512);
      acc[ot] = __builtin_amdgcn_mfma_f32_16x16x32_f16(af0, b0, acc[ot], 0, 0, 0);
      acc[ot] = __builtin_amdgcn_mfma_f32_16x16x32_f16(af1, b1, acc[ot], 0, 0, 0);
    }
  }
  __syncthreads();   // S dead; Dbuf aliases it
  #pragma unroll
  for (int ot = 0; ot < 6; ++ot)
    #pragma unroll
    for (int r = 0; r < 4; ++r)
      Dbuf[(ot * 16 + m16) * 65 + wavei * 16 + quad * 4 + r] = acc[ot][r];
  __syncthreads();
  for (int i = threadIdx.x; i < 81 * 64; i += 256) {
    int oc = i >> 6, p = i & 63;
    off[(size_t)oc * THW_ + p0 + p] = Dbuf[oc * 65 + p] + ob[oc];
  }
}

// Deformable sample + MFMA GEMM: out[64 oc][64 p] per block, K = 27x64.
// Meta split into msite/mwt tables. Gather is two-phase: all 64 loads issued
// into a register stage (one VMEM round trip), then consumed.
__global__ __launch_bounds__(256, 4) void deform(
    const float* __restrict__ x,
    const ushort_t* __restrict__ xt,
    const float* __restrict__ off,
    const ushort_t* __restrict__ wfrag,
    const float* __restrict__ gamma,
    float* __restrict__ out)
{
  __shared__ __align__(16) char lds[16640];   // S(9216)+msite(2048)+mwt(2048) | Dbuf
  ushort_t* S = (ushort_t*)lds;               // [64 pos][72 f16]
  unsigned* msite = (unsigned*)(lds + 9216);  // [64 pos][8]
  unsigned* mwt   = (unsigned*)(lds + 11264); // [64 pos][8]
  float* Dbuf = (float*)lds;                  // [64 oc][65]
  int lane = threadIdx.x & 63;
  int wavei = __builtin_amdgcn_readfirstlane(threadIdx.x >> 6);
  int quad = lane >> 4;
  int m16 = lane & 15;
  int hlf = lane >> 5;
  int lo4 = (lane & 31) * 4;
  int p0 = blockIdx.x * 64;
  int t = p0 >> 14;
  int h = (p0 >> 7) & 127;
  int w0 = p0 & 127;
  XtBuf xb = mkbuf(xt);

  floatx4 acc[4];
  #pragma unroll
  for (int i = 0; i < 4; ++i) acc[i] = (floatx4){0.f, 0.f, 0.f, 0.f};

  int pl = wavei * 16 + m16;
  int pm = p0 + pl;
  int aq = quad >> 1, bq = quad & 1;
  const float* offT = off + pm;

  float dt_c = offT[(size_t)(0 * NT + 0) * THW_];
  float dh_c = offT[(size_t)(1 * NT + 0) * THW_];
  float dw_c = offT[(size_t)(2 * NT + 0) * THW_];

  #pragma unroll 1
  for (int k = 0; k < NT; ++k) {
    int kn = (k + 1 < NT) ? k + 1 : NT - 1;
    float dt_n = offT[(size_t)(0 * NT + kn) * THW_];
    float dh_n = offT[(size_t)(1 * NT + kn) * THW_];
    float dw_n = offT[(size_t)(2 * NT + kn) * THW_];

    int kt = k / 9, kh = (k / 3) % 3, kw = k % 3;
    // --- meta: lane handles position pl, (t,h)-corner (aq,bq), both w-corners
    float tf = (float)(t + kt - 1) + dt_c;
    float hf = (float)(h + kh - 1) + dh_c;
    float wf = (float)(w0 + pl + kw - 1) + dw_c;
    float tF = floorf(tf), hF = floorf(hf), wF = floorf(wf);
    float lt = tf - tF, lh_ = hf - hF, lw_ = wf - wF;
    int t0 = (int)tF, h0 = (int)hF, wq_ = (int)wF;
    int ti = t0 + aq;
    float wt_ = (aq ? lt : 1.f - lt) * (((unsigned)ti < 4u) ? 1.f : 0.f);
    int tic = min(max(ti, 0), 3);
    int hi = h0 + bq;
    float wh_ = (bq ? lh_ : 1.f - lh_) * (((unsigned)hi < 128u) ? 1.f : 0.f);
    int hic = min(max(hi, 0), 127);
    int base2 = tic * HW_ + hic * Ww;
    float bw = wt_ * wh_;
    int wi0 = wq_;
    float ww0 = (1.f - lw_) * (((unsigned)wi0 < 128u) ? 1.f : 0.f);
    int wi0c = min(max(wi0, 0), 127);
    int wi1 = wq_ + 1;
    float ww1 = lw_ * (((unsigned)wi1 < 128u) ? 1.f : 0.f);
    int wi1c = min(max(wi1, 0), 127);
    uint2 sp_;
    sp_.x = (unsigned)(base2 + wi0c) << 7;
    sp_.y = (unsigned)(base2 + wi1c) << 7;
    *(uint2*)&msite[pl * 8 + quad * 2] = sp_;
    uint2 wp_;
    wp_.x = pk2(bw * ww0);
    wp_.y = pk2(bw * ww1);
    *(uint2*)&mwt[pl * 8 + quad * 2] = wp_;

    // --- phase 1: issue all 64 gather loads into register stage
    unsigned dreg[8][8];
    #pragma unroll
    for (int j = 0; j < 8; ++j) {
      int prow = wavei * 16 + j * 2 + hlf;
      const uint4* spp = (const uint4*)&msite[prow * 8];
      uint4 s03 = spp[0], s47 = spp[1];
      dreg[j][0] = xload(xb, s03.x + lo4);
      dreg[j][1] = xload(xb, s03.y + lo4);
      dreg[j][2] = xload(xb, s03.z + lo4);
      dreg[j][3] = xload(xb, s03.w + lo4);
      dreg[j][4] = xload(xb, s47.x + lo4);
      dreg[j][5] = xload(xb, s47.y + lo4);
      dreg[j][6] = xload(xb, s47.z + lo4);
      dreg[j][7] = xload(xb, s47.w + lo4);
    }
    // --- phase 2: consume in issue order
    #pragma unroll
    for (int j = 0; j < 8; ++j) {
      int prow = wavei * 16 + j * 2 + hlf;
      const uint4* wpp = (const uint4*)&mwt[prow * 8];
      uint4 w03 = wpp[0], w47 = wpp[1];
      U32H2 z; z.u = 0;
      f16x2 a2l = z.h, a2h = z.h;
      U32H2 du, wu;
      du.u = dreg[j][0]; wu.u = w03.x; a2l += wu.h * du.h;
      du.u = dreg[j][1]; wu.u = w03.y; a2h += wu.h * du.h;
      du.u = dreg[j][2]; wu.u = w03.z; a2l += wu.h * du.h;
      du.u = dreg[j][3]; wu.u = w03.w; a2h += wu.h * du.h;
      du.u = dreg[j][4]; wu.u = w47.x; a2l += wu.h * du.h;
      du.u = dreg[j][5]; wu.u = w47.y; a2h += wu.h * du.h;
      du.u = dreg[j][6]; wu.u = w47.z; a2l += wu.h * du.h;
      du.u = dreg[j][7]; wu.u = w47.w; a2h += wu.h * du.h;
      U32H2 res;
      res.h = a2l + a2h;
      *(unsigned*)((char*)S + prow * 144 + lo4) = res.u;
    }
    // --- MFMA
    const ushort_t* srow = S + (wavei * 16 + m16) * 72 + quad * 8;
    f16x8 af0 = *(const f16x8*)srow;
    f16x8 af1 = *(const f16x8*)(srow + 32);
    #pragma unroll
    for (int ot = 0; ot < 4; ++ot) {
      const ushort_t* wb = wfrag + (size_t)((k * 4 + ot) * 2) * 512 + lane * 8;
      f16x8 b0 = *(const f16x8*)(wb);
      f16x8 b1 = *(const f16x8*)(wb + 512);
      acc[ot] = __builtin_amdgcn_mfma_f32_16x16x32_f16(af0, b0, acc[ot], 0, 0, 0);
      acc[ot] = __builtin_amdgcn_mfma_f32_16x16x32_f16(af1, b1, acc[ot], 0, 0, 0);
    }
    dt_c = dt_n; dh_c = dh_n; dw_c = dw_n;
  }
  __syncthreads();   // S/meta dead; Dbuf aliases them
  #pragma unroll
  for (int ot = 0; ot < 4; ++ot)
    #pragma unroll
    for (int r = 0; r < 4; ++r)
      Dbuf[(ot * 16 + m16) * 65 + wavei * 16 + quad * 4 + r] = acc[ot][r];
  __syncthreads();
  float g = gamma[0];
  for (int i = threadIdx.x; i < 64 * 64; i += 256) {
    int oc = i >> 6, p = i & 63;
    size_t oi = (size_t)t * CHW_ + (size_t)oc * HW_ + (size_t)h * Ww + w0 + p;
    out[oi] = fmaf(g, Dbuf[oc * 65 + p], x[oi]);
  }
}

extern "C" void kernel_launch(void* const* d_in, const int* in_sizes, int n_in,
                              void* d_out, int out_size, void* d_ws, size_t ws_size,
                              hipStream_t stream) {
  (void)in_sizes; (void)n_in; (void)out_size; (void)ws_size;
  const float* x        = (const float*)d_in[0];
  const float* offset_w = (const float*)d_in[1];
  const float* offset_b = (const float*)d_in[2];
  const float* weight   = (const float*)d_in[3];
  const float* gamma    = (const float*)d_in[4];
  float* out = (float*)d_out;
  float* wsf = (float*)d_ws;
  float*    off    = wsf;                               // 5308416 f32
  ushort_t* xt     = (ushort_t*)(wsf + 5308416);        // 4194304 f16
  ushort_t* wfrag  = (ushort_t*)(wsf + 7405568);        // 110592 f16
  ushort_t* w2frag = (ushort_t*)(wsf + 7460864);        // 165888 f16

  hipLaunchKernelGGL(prep, dim3(648), dim3(256), 0, stream,
                     offset_w, weight, w2frag, wfrag);
  hipLaunchKernelGGL(transpose_x, dim3(1024), dim3(256), 0, stream, x, xt);
  hipLaunchKernelGGL(offconv, dim3(1024), dim3(256), 0, stream,
                     xt, w2frag, offset_b, off);
  hipLaunchKernelGGL(deform, dim3(1024), dim3(256), 0, stream,
                     x, xt, off, wfrag, gamma, out);
}